// Round 6
// baseline (766.221 us; speedup 1.0000x reference)
//
#include <hip/hip_runtime.h>
#include <hip/hip_bf16.h>
#include <math.h>
#include <float.h>

#define BB    64
#define CCH   256
#define KKE   1024
#define HWN   1024
#define NTOT  (BB*HWN)          // 65536
#define OUT_ELE (BB*CCH*HWN)    // 16777216
#define LOSS_OFF 0
#define OUT_OFF  1
#define PERP_OFF (1 + OUT_ELE)
#define ENC_OFF  (2 + OUT_ELE)   // byte off % 16 == 8 -> float2 stores only

// workspace layout (bytes)
#define WS_IDX    0               // int[65536]
#define WS_ANORM  262144          // float[65536]
#define WS_HIST   524288          // uint[1024]
#define WS_BNORM  528384          // float[1024]
#define WS_MISC   532480          // [0]=lossacc (float), [1]=counter (int)
#define WS_LIST   536576          // int[65536]
#define WS_EMBT   798720          // float[256*1024] -> ends 1847296
#define WS_EHI    1847296         // bf16 frag-order [chunk8][ktile64][lane64][8] = 512KB
#define WS_ELO    2371584         // 512KB -> ends 2895872
#define WS_CD1    2895872         // float[8][65536]
#define WS_CK1    4993024         // int[8][65536]
#define WS_CD2    7090176         // float[8][65536] -> ends 9187328
#define WS_AHI    16777216        // bf16 frag-order [chunk8][ntile4096][lane64][8] = 32MB
#define WS_ALO    50331648        // 32MB -> ends 83886080 (~80MB total)

typedef __attribute__((ext_vector_type(4))) float f32x4;
typedef __attribute__((ext_vector_type(8))) short s16x8;

#define TAU 2e-4f

#define GLOAD_LDS(gptr, ldsptr) \
    __builtin_amdgcn_global_load_lds((const __attribute__((address_space(1))) unsigned int*)(gptr), \
                                     (__attribute__((address_space(3))) unsigned int*)(ldsptr), 16, 0, 0)

// merge two (d1,k1,d2) candidate sets; first-index tie-break
__device__ inline void merge_cand(float& d1, int& k1, float& d2,
                                  float od1, int ok1, float od2) {
    bool w = (od1 < d1) || (od1 == d1 && ok1 < k1);
    float loser_d1 = w ? d1 : od1;
    float winner_d2 = w ? od2 : d2;
    d2 = fminf(winner_d2, loser_d1);
    if (w) { d1 = od1; k1 = ok1; }
}

// ---------------- Kernel 1: transpose emb, ||e||^2 fp64, frag-order bf16 split, zero accums
// frag order: e[code][c] -> ehi[ ((chunk*64 + code>>4)*64 + (code&15 | ((c>>3)&3)<<4))*8 + (c&7) ]
__global__ __launch_bounds__(256) void prep_kernel(const float* __restrict__ emb,
                                                   float* __restrict__ embT,
                                                   float* __restrict__ bnorm,
                                                   short* __restrict__ ehi,
                                                   short* __restrict__ elo,
                                                   unsigned int* __restrict__ hist,
                                                   float* __restrict__ misc) {
    const int k = blockIdx.x;     // 0..1023 = code
    const int t = threadIdx.x;    // 0..255 = c
    float v = emb[k*CCH + t];
    embT[(size_t)t*KKE + k] = v;
    __hip_bfloat16 h = __float2bfloat16(v);
    float hf = __bfloat162float(h);
    __hip_bfloat16 l = __float2bfloat16(v - hf);
    const int chunk = t >> 5;
    const int lane  = (k & 15) | (((t >> 3) & 3) << 4);
    const size_t eoff = ((size_t)(chunk*64 + (k >> 4))*64 + lane)*8 + (t & 7);
    ehi[eoff] = *(short*)&h;
    elo[eoff] = *(short*)&l;
    double sq = (double)v * (double)v;
    #pragma unroll
    for (int off = 32; off; off >>= 1) sq += __shfl_down(sq, off);
    __shared__ double wred[4];
    const int wave = t >> 6, ln = t & 63;
    if (ln == 0) wred[wave] = sq;
    __syncthreads();
    if (t == 0) bnorm[k] = (float)(wred[0] + wred[1] + wred[2] + wred[3]);
    if (blockIdx.x < 4) hist[blockIdx.x*256 + t] = 0u;
    if (blockIdx.x == 4 && t == 0) { misc[0] = 0.0f; ((int*)misc)[1] = 0; }
}

// ---------------- Kernel 1b: bf16-split A into frag order + fused ||x||^2
// block = 32 n rows x 256 c. grid 2048.
__global__ __launch_bounds__(256) void split_kernel(const float* __restrict__ inp,
                                                    short* __restrict__ ahi,
                                                    short* __restrict__ alo,
                                                    float* __restrict__ anorm) {
    __shared__ float xs[256][32];     // [c][n_local] 32KB
    __shared__ double dred[8][32];
    const int t = threadIdx.x;
    const int n0 = blockIdx.x * 32;
    const int b = n0 >> 10;
    const int hw0 = n0 & 1023;
    const float* src = inp + (size_t)b*CCH*HWN + hw0;
    // load: float4 per thread, 32 c per iter, contiguous LDS writes
    const int n4 = (t & 7) * 4, cl = t >> 3;
    #pragma unroll
    for (int c0 = 0; c0 < CCH; c0 += 32) {
        float4 v = *(const float4*)&src[(size_t)(c0 + cl)*HWN + n4];
        *(float4*)&xs[c0 + cl][n4] = v;
    }
    __syncthreads();
    // anorm partials (8 parts x 32 n)
    {
        const int nl = t & 31, part = t >> 5;
        double s = 0.0;
        #pragma unroll 8
        for (int c = 0; c < 32; ++c) {
            float v = xs[part*32 + c][nl];
            s += (double)v * (double)v;
        }
        dred[part][nl] = s;
    }
    __syncthreads();
    if (t < 32) {
        double s = 0.0;
        #pragma unroll
        for (int p = 0; p < 8; ++p) s += dred[p][t];
        anorm[n0 + t] = (float)s;
    }
    // frag-order split writes: slots [chunk8][ntile2][lane64], 4 per thread
    const int ntg0 = n0 >> 4;
    #pragma unroll
    for (int i = 0; i < 4; ++i) {
        const int s = t + 256*i;
        const int chunk = s >> 7;
        const int nt = (s >> 6) & 1;
        const int lane = s & 63;
        const int m = lane & 15, q = lane >> 4;
        short hsv[8], lsv[8];
        #pragma unroll
        for (int j = 0; j < 8; ++j) {
            float v = xs[chunk*32 + q*8 + j][nt*16 + m];
            __hip_bfloat16 h = __float2bfloat16(v);
            float hf = __bfloat162float(h);
            __hip_bfloat16 l = __float2bfloat16(v - hf);
            hsv[j] = *(short*)&h; lsv[j] = *(short*)&l;
        }
        const size_t off = ((size_t)(chunk*4096 + ntg0 + nt)*64 + lane)*8;
        *(s16x8*)&ahi[off] = *(s16x8*)&hsv[0];
        *(s16x8*)&alo[off] = *(s16x8*)&lsv[0];
    }
}

// ---------------- Kernel 2: MFMA distance + per-k-block argmin candidates
// grid (8 k-blocks, 512 n-blocks), 256 thr = 4 waves in 2x2.
// Staging via global_load_lds(16B) from frag-ordered buffers; frag ds_read_b128
// are contiguous 1KB segments -> conflict-free. No VALU conversion in loop.
__global__ __launch_bounds__(256, 4) void argmin_mfma(const short* __restrict__ ahi,
                                                      const short* __restrict__ alo,
                                                      const short* __restrict__ ehi,
                                                      const short* __restrict__ elo,
                                                      const float* __restrict__ anorm,
                                                      const float* __restrict__ bnorm,
                                                      float* __restrict__ cd1,
                                                      int* __restrict__ ck1,
                                                      float* __restrict__ cd2) {
    __shared__ short Ah[8*512];    // 8 ntiles x 1KB
    __shared__ short Al[8*512];
    __shared__ short Bh[8*512];    // 8 ktiles x 1KB
    __shared__ short Bl[8*512];
    __shared__ float m_d1[2][128];
    __shared__ float m_d2[2][128];
    __shared__ int   m_k1[2][128];

    const int t    = threadIdx.x;
    const int w    = t >> 6;
    const int lane = t & 63;
    const int q    = lane >> 4;
    const int l15  = lane & 15;
    const int wn   = (w & 1) * 64;   // wave n-offset in tile
    const int wkh  = w >> 1;         // wave k-half
    const int wk   = wkh * 64;
    const int k0     = blockIdx.x * 128;
    const int ktile0 = blockIdx.x * 8;
    const int n0     = blockIdx.y * 128;
    const int ntg0   = n0 >> 4;

    f32x4 acc[4][4];
    #pragma unroll
    for (int i = 0; i < 4; ++i)
        #pragma unroll
        for (int j = 0; j < 4; ++j) acc[i][j] = (f32x4){0.f,0.f,0.f,0.f};

    for (int chunk = 0; chunk < 8; ++chunk) {
        __syncthreads();   // previous chunk's frag reads done before overwrite
        #pragma unroll
        for (int i = 0; i < 4; ++i) {
            const int sel = w*4 + i;       // 0..15, wave-uniform
            const int rt  = sel & 7;       // tile index
            const bool hi = (sel < 8);
            // A tile rt
            {
                const short* g = hi ? ahi : alo;
                short* d = hi ? &Ah[rt*512] : &Al[rt*512];
                GLOAD_LDS(g + ((size_t)(chunk*4096 + ntg0 + rt)*64 + lane)*8, d);
            }
            // B tile rt
            {
                const short* g = hi ? ehi : elo;
                short* d = hi ? &Bh[rt*512] : &Bl[rt*512];
                GLOAD_LDS(g + ((size_t)(chunk*64 + ktile0 + rt)*64 + lane)*8, d);
            }
        }
        __syncthreads();   // vmcnt(0) drain: LDS tiles complete
        s16x8 ah4[4], al4[4];
        #pragma unroll
        for (int rg = 0; rg < 4; ++rg) {
            const int nt = (w & 1)*4 + rg;
            ah4[rg] = *(s16x8*)&Ah[nt*512 + lane*8];
            al4[rg] = *(s16x8*)&Al[nt*512 + lane*8];
        }
        #pragma unroll
        for (int ct = 0; ct < 4; ++ct) {
            const int kt = wkh*4 + ct;
            s16x8 bh = *(s16x8*)&Bh[kt*512 + lane*8];
            s16x8 bl = *(s16x8*)&Bl[kt*512 + lane*8];
            #pragma unroll
            for (int rg = 0; rg < 4; ++rg) {
                acc[rg][ct] = __builtin_amdgcn_mfma_f32_16x16x32_bf16(ah4[rg], bh, acc[rg][ct], 0, 0, 0);
                acc[rg][ct] = __builtin_amdgcn_mfma_f32_16x16x32_bf16(ah4[rg], bl, acc[rg][ct], 0, 0, 0);
                acc[rg][ct] = __builtin_amdgcn_mfma_f32_16x16x32_bf16(al4[rg], bh, acc[rg][ct], 0, 0, 0);
            }
        }
    }

    // ---- epilogue: d = (anorm+bnorm) - 2*dot; per-row best/2nd over wave's 64 k
    float bnv[4];
    #pragma unroll
    for (int ct = 0; ct < 4; ++ct) bnv[ct] = bnorm[k0 + wk + ct*16 + l15];

    #pragma unroll
    for (int rg = 0; rg < 4; ++rg) {
        #pragma unroll
        for (int reg = 0; reg < 4; ++reg) {
            const int nl = wn + rg*16 + q*4 + reg;         // C/D: row = quad*4+reg
            const float a = anorm[n0 + nl];
            float d1 = FLT_MAX, d2 = FLT_MAX; int k1 = 0;
            #pragma unroll
            for (int ct = 0; ct < 4; ++ct) {
                float s = a + bnv[ct];
                float d = s - 2.0f * acc[rg][ct][reg];
                int   k = k0 + wk + ct*16 + l15;           // C/D: col = lane&15
                if (d < d1 || (d == d1 && k < k1)) { d2 = d1; d1 = d; k1 = k; }
                else d2 = fminf(d2, d);
            }
            #pragma unroll
            for (int off = 1; off < 16; off <<= 1) {
                float od1 = __shfl_xor(d1, off);
                int   ok1 = __shfl_xor(k1, off);
                float od2 = __shfl_xor(d2, off);
                merge_cand(d1, k1, d2, od1, ok1, od2);
            }
            if (l15 == 0) {
                m_d1[wkh][nl] = d1; m_k1[wkh][nl] = k1; m_d2[wkh][nl] = d2;
            }
        }
    }
    __syncthreads();
    if (t < 128) {
        float d1 = m_d1[0][t]; int k1 = m_k1[0][t]; float d2 = m_d2[0][t];
        merge_cand(d1, k1, d2, m_d1[1][t], m_k1[1][t], m_d2[1][t]);
        const size_t o = (size_t)blockIdx.x*NTOT + n0 + t;
        cd1[o] = d1; ck1[o] = k1; cd2[o] = d2;
    }
}

// ---------------- Kernel 3: merge 8 k-block candidates, flag near-ties
__global__ __launch_bounds__(256) void reduce_kernel(const float* __restrict__ cd1,
                                                     const int* __restrict__ ck1,
                                                     const float* __restrict__ cd2,
                                                     int* __restrict__ idx,
                                                     int* __restrict__ list,
                                                     int* __restrict__ counter) {
    const int n = blockIdx.x*256 + threadIdx.x;
    float d1 = cd1[n]; int k1 = ck1[n]; float d2 = cd2[n];
    #pragma unroll
    for (int kb = 1; kb < 8; ++kb) {
        const size_t o = (size_t)kb*NTOT + n;
        merge_cand(d1, k1, d2, cd1[o], ck1[o], cd2[o]);
    }
    idx[n] = k1;
    if (d2 - d1 < TAU) {
        int p = atomicAdd(counter, 1);
        list[p] = n;
    }
}

// ---------------- Kernel 4: exact fp32 rescore (reference sequential-c semantics)
__global__ __launch_bounds__(256) void rescore_kernel(const float* __restrict__ inp,
                                                      const float* __restrict__ embT,
                                                      const float* __restrict__ anorm,
                                                      const float* __restrict__ bnorm,
                                                      const int* __restrict__ list,
                                                      const int* __restrict__ counter,
                                                      int* __restrict__ idx) {
    __shared__ float xs[256];
    __shared__ float rd[256];
    __shared__ int   rk[256];
    const int t = threadIdx.x;
    const int cnt = *counter;
    for (int f = blockIdx.x; f < cnt; f += gridDim.x) {
        const int n = list[f];
        const int b = n >> 10, hw = n & 1023;
        __syncthreads();
        xs[t] = inp[(size_t)b*CCH*HWN + (size_t)t*HWN + hw];
        __syncthreads();
        float dot0 = 0.f, dot1 = 0.f, dot2 = 0.f, dot3 = 0.f;
        #pragma unroll 4
        for (int c = 0; c < CCH; ++c) {
            const float xc = xs[c];
            const float* row = embT + (size_t)c*KKE + t;
            dot0 += xc * row[0];
            dot1 += xc * row[256];
            dot2 += xc * row[512];
            dot3 += xc * row[768];
        }
        const float a = anorm[n];
        float bd = FLT_MAX; int bk = 0;
        float dots[4] = {dot0, dot1, dot2, dot3};
        #pragma unroll
        for (int kk = 0; kk < 4; ++kk) {
            const int k = kk*256 + t;
            float s = a + bnorm[k];
            float d = s - 2.0f * dots[kk];
            if (d < bd || (d == bd && k < bk)) { bd = d; bk = k; }
        }
        rd[t] = bd; rk[t] = bk;
        __syncthreads();
        for (int stride = 128; stride; stride >>= 1) {
            if (t < stride) {
                float od = rd[t+stride]; int ok = rk[t+stride];
                if (od < rd[t] || (od == rd[t] && ok < rk[t])) { rd[t] = od; rk[t] = ok; }
            }
            __syncthreads();
        }
        if (t == 0) idx[n] = rk[0];
    }
}

// ---------------- Kernel 5: encodings one-hot + histogram (16 rows/block)
__global__ __launch_bounds__(256) void onehot_kernel(const int* __restrict__ idx,
                                                     float* __restrict__ enc,
                                                     unsigned int* __restrict__ hist) {
    const int t = threadIdx.x;
    const int j4 = t * 4;
    for (int r = 0; r < 16; ++r) {
        const int n = blockIdx.x*16 + r;
        const int k = idx[n];
        float2 v0 = {0.0f, 0.0f}, v1 = {0.0f, 0.0f};
        if (k == j4)     v0.x = 1.0f;
        if (k == j4 + 1) v0.y = 1.0f;
        if (k == j4 + 2) v1.x = 1.0f;
        if (k == j4 + 3) v1.y = 1.0f;
        float* row = enc + (size_t)n * KKE;
        *(float2*)&row[j4]     = v0;
        *(float2*)&row[j4 + 2] = v1;
        if (t == 0) atomicAdd(&hist[k], 1u);
    }
}

// ---------------- Kernel 6: out = gather(e), loss partials
__global__ __launch_bounds__(256) void out_loss_kernel(const float* __restrict__ inp,
                                                       const float* __restrict__ embT,
                                                       const int* __restrict__ idx,
                                                       float* __restrict__ out,
                                                       float* __restrict__ lossacc) {
    const int t = threadIdx.x;
    const size_t stride = (size_t)gridDim.x * 256;
    float lsum = 0.0f;
    for (size_t m = (size_t)blockIdx.x * 256 + t; m < (size_t)OUT_ELE; m += stride) {
        int hw = (int)(m & 1023);
        int c  = (int)((m >> 10) & 255);
        int b  = (int)(m >> 18);
        int k  = idx[b*HWN + hw];
        float e = embT[(size_t)c*KKE + k];
        float x = inp[m];
        out[m] = e;
        float df = e - x;
        lsum += df * df;
    }
    #pragma unroll
    for (int off = 32; off; off >>= 1) lsum += __shfl_down(lsum, off);
    __shared__ float wred[4];
    const int wave = t >> 6, lane = t & 63;
    if (lane == 0) wred[wave] = lsum;
    __syncthreads();
    if (t == 0) atomicAdd(lossacc, wred[0] + wred[1] + wred[2] + wred[3]);
}

// ---------------- Kernel 7: finalize
__global__ __launch_bounds__(1024) void final_kernel(const unsigned int* __restrict__ hist,
                                                     const float* __restrict__ lossacc,
                                                     float* __restrict__ d_out) {
    const int t = threadIdx.x;
    float p = (float)hist[t] * (1.0f / 65536.0f);
    float v = p * logf(p + 1e-10f);
    #pragma unroll
    for (int off = 32; off; off >>= 1) v += __shfl_down(v, off);
    __shared__ float wred[16];
    const int wave = t >> 6, lane = t & 63;
    if (lane == 0) wred[wave] = v;
    __syncthreads();
    if (t == 0) {
        float s = 0.0f;
        #pragma unroll
        for (int i = 0; i < 16; ++i) s += wred[i];
        d_out[PERP_OFF] = expf(-s);
        d_out[LOSS_OFF] = 1.25f * (*lossacc) * (1.0f / (float)OUT_ELE);
    }
}

extern "C" void kernel_launch(void* const* d_in, const int* in_sizes, int n_in,
                              void* d_out, int out_size, void* d_ws, size_t ws_size,
                              hipStream_t stream) {
    (void)in_sizes; (void)n_in; (void)out_size; (void)ws_size;
    const float* inp = (const float*)d_in[0];
    const float* emb = (const float*)d_in[1];
    float* out = (float*)d_out;
    char* ws = (char*)d_ws;
    int*          idx     = (int*)(ws + WS_IDX);
    float*        anorm   = (float*)(ws + WS_ANORM);
    unsigned int* hist    = (unsigned int*)(ws + WS_HIST);
    float*        bnorm   = (float*)(ws + WS_BNORM);
    float*        misc    = (float*)(ws + WS_MISC);
    int*          list    = (int*)(ws + WS_LIST);
    float*        embT    = (float*)(ws + WS_EMBT);
    short*        ehi     = (short*)(ws + WS_EHI);
    short*        elo     = (short*)(ws + WS_ELO);
    float*        cd1     = (float*)(ws + WS_CD1);
    int*          ck1     = (int*)(ws + WS_CK1);
    float*        cd2     = (float*)(ws + WS_CD2);
    short*        ahi     = (short*)(ws + WS_AHI);
    short*        alo     = (short*)(ws + WS_ALO);
    int*          counter = ((int*)misc) + 1;

    prep_kernel<<<dim3(KKE), dim3(256), 0, stream>>>(emb, embT, bnorm, ehi, elo, hist, misc);
    split_kernel<<<dim3(2048), dim3(256), 0, stream>>>(inp, ahi, alo, anorm);
    argmin_mfma<<<dim3(8, 512), dim3(256), 0, stream>>>(ahi, alo, ehi, elo, anorm, bnorm, cd1, ck1, cd2);
    reduce_kernel<<<dim3(256), dim3(256), 0, stream>>>(cd1, ck1, cd2, idx, list, counter);
    rescore_kernel<<<dim3(512), dim3(256), 0, stream>>>(inp, embT, anorm, bnorm, list, counter, idx);
    onehot_kernel<<<dim3(4096), dim3(256), 0, stream>>>(idx, out + ENC_OFF, hist);
    out_loss_kernel<<<dim3(4096), dim3(256), 0, stream>>>(inp, embT, idx, out + OUT_OFF, misc);
    final_kernel<<<dim3(1), dim3(1024), 0, stream>>>(hist, misc, out);
}